// Round 17
// baseline (623.455 us; speedup 1.0000x reference)
//
#include <hip/hip_runtime.h>
#include <math.h>
#include <stdint.h>

typedef unsigned short u16;
typedef __attribute__((ext_vector_type(8))) short bf16x8;
typedef __attribute__((ext_vector_type(4))) float f32x4;
typedef __attribute__((ext_vector_type(4))) unsigned short u16x4;

#define N_ 4096
#define D_ 1024
#define F_ 4096
#define M_ 2048
#define KG 307

__device__ __forceinline__ u16 f2bf(float f) {
  unsigned int u = __float_as_uint(f);
  unsigned int r = u + 0x7fffu + ((u >> 16) & 1u);
  return (u16)(r >> 16);
}

__device__ __forceinline__ float bf2f(u16 u) {
  return __uint_as_float((unsigned)u << 16);
}

// GELU via Abramowitz-Stegun 7.1.26 erf (|err| <= 1.5e-7). Verified r16.
__device__ __forceinline__ float gelu_fast(float t) {
  float x = t * 0.70710678118654752f;
  float ax = fabsf(x);
  float u = __builtin_amdgcn_rcpf(fmaf(0.3275911f, ax, 1.0f));
  float poly =
      u * fmaf(u, fmaf(u, fmaf(u, fmaf(u, 1.061405429f, -1.453152027f), 1.421413741f),
                       -0.284496736f),
               0.254829592f);
  float erfabs = fmaf(-poly, __expf(-ax * ax), 1.0f);
  float er = copysignf(erfabs, x);
  return 0.5f * t * (1.0f + er);
}

__device__ __forceinline__ void gl_lds16(const u16* g, u16* l) {
  __builtin_amdgcn_global_load_lds(
      (__attribute__((address_space(1))) void*)(void*)g,
      (__attribute__((address_space(3))) void*)(void*)l,
      16, 0, 0);
}

enum { E_QKV = 0, E_SMASK = 1, E_PART = 2, E_GELU = 3 };
#define SMEM_BYTES 131072

// ============================================================================
// 256xTN 8-wave GEMM (TN in {256,192}), BK=64, cross-phase pipelined.
// B staged in 64-row chunks (8KB = exactly 1 load/thread -> per-thread vmcnt
// ledger identical for both TN: 2 chunks at ph2, rest post-ph3-barrier).
// E_QKV: bf16 q|k row-major + v transposed. E_SMASK: bf16 scores.
// E_PART: bf16 split-K partials (z0 carries bias). E_GELU: bias+A&S-GELU.
// C[M,N] = A[M,K] @ B[N,K]^T  (A,B bf16 row-major k-contiguous)
// ============================================================================
template <int EPI, int TN = 256>
__global__ __launch_bounds__(512, 2) void gemm256(
    const u16* __restrict__ A, const u16* __restrict__ B,
    void* __restrict__ C, void* __restrict__ C2,
    int gridM, int gridN, int Ndim, int Ksp, int lda, int ldb, long zstr,
    const float* __restrict__ bias, const unsigned char* __restrict__ mask,
    float scale) {
  constexpr int NV = TN / 64;       // B fragments per wave (4 or 3)
  constexpr int WCOLS = TN / 4;     // cols per wave (64 or 48)
  constexpr int NBCH = TN / 64;     // 64-row B chunks per tile (4 or 3)
  constexpr int BBYTES = TN * 128;  // B buffer bytes per dbuf (32K or 24K)
  extern __shared__ __align__(16) char smem[];
  const int tid = threadIdx.x;
  const int lane = tid & 63;
  const int wid = tid >> 6;   // 0..7
  const int wr = wid >> 2;    // 0..1
  const int wc = wid & 3;     // 0..3
  const int lr = lane & 15;
  const int lk = lane >> 4;

  const int nwg = gridM * gridN;
  const int bid = blockIdx.x;
  const int q8 = nwg >> 3, r8 = nwg & 7;
  const int xcd = bid & 7, ii = bid >> 3;
  int wg = (xcd < r8 ? xcd * (q8 + 1) : r8 * (q8 + 1) + (xcd - r8) * q8) + ii;
  const int rowblk = wg / (gridN << 2);
  const int rem = wg - rowblk * (gridN << 2);
  const int mrem = gridM - (rowblk << 2);
  int mtile, ntile;
  if (mrem >= 4) {
    ntile = rem >> 2;
    mtile = (rowblk << 2) + (rem & 3);
  } else {
    ntile = rem / mrem;
    mtile = (rowblk << 2) + (rem - ntile * mrem);
  }
  const long bm = (long)mtile * 256;
  const long bn = (long)ntile * TN;
  const long koff = (long)blockIdx.y * Ksp;
  const int NT = Ksp >> 6;

  auto stA = [&](int t, int h) {  // A half-tile: 128 rows, 2 loads/thread
    char* base = smem + ((t & 1) << 15) + (h << 14);
    const long k0 = koff + ((long)t << 6);
#pragma unroll
    for (int j = 0; j < 2; ++j) {
      int o = tid + (j << 9);
      int r = o >> 3, s = o & 7;
      gl_lds16(A + (bm + (h << 7) + r) * (long)lda + k0 + ((s ^ (r & 7)) << 3),
               (u16*)(base + o * 16));
    }
  };
  auto stB = [&](int t, int c) {  // B chunk: 64 rows, 1 load/thread
    char* base = smem + 65536 + (t & 1) * BBYTES + (c << 13);
    const long k0 = koff + ((long)t << 6);
    int o = tid;
    int r = o >> 3, s = o & 7;
    gl_lds16(B + (bn + (c << 6) + r) * (long)ldb + k0 + ((s ^ (r & 7)) << 3),
             (u16*)(base + o * 16));
  };

  bf16x8 avA[2][2], avB[2][2], bv[NV][2];
  f32x4 acc[8][NV];
#pragma unroll
  for (int m = 0; m < 8; ++m)
#pragma unroll
    for (int n = 0; n < NV; ++n) acc[m][n] = f32x4{0.f, 0.f, 0.f, 0.f};

  auto rdAV = [&](bf16x8(&av)[2][2], const char* Ab_, int q) {
#pragma unroll
    for (int e = 0; e < 2; ++e)
#pragma unroll
      for (int ks = 0; ks < 2; ++ks) {
        int r = (wr << 7) + (q << 5) + (e << 4) + lr;
        av[e][ks] = *(const bf16x8*)(Ab_ + r * 128 + ((((ks << 2) | lk) ^ (r & 7)) << 4));
      }
  };
  auto rdBV = [&](const char* Bb_) {
#pragma unroll
    for (int n = 0; n < NV; ++n)
#pragma unroll
      for (int ks = 0; ks < 2; ++ks) {
        int r = wc * WCOLS + (n << 4) + lr;
        bv[n][ks] = *(const bf16x8*)(Bb_ + r * 128 + ((((ks << 2) | lk) ^ (r & 7)) << 4));
      }
  };

#define MM(Q, AV)                                                              \
  __builtin_amdgcn_s_setprio(1);                                               \
  _Pragma("unroll") for (int e = 0; e < 2; ++e)                                \
  _Pragma("unroll") for (int n = 0; n < NV; ++n)                               \
  _Pragma("unroll") for (int ks = 0; ks < 2; ++ks)                             \
      acc[((Q) << 1) | e][n] = __builtin_amdgcn_mfma_f32_16x16x32_bf16(        \
          AV[e][ks], bv[n][ks], acc[((Q) << 1) | e][n], 0, 0, 0);              \
  __builtin_amdgcn_s_setprio(0);                                               \
  __builtin_amdgcn_sched_barrier(0);

  // prologue: A(0) + B(0) fully, then B(1) fully
  stA(0, 0);
  stA(0, 1);
#pragma unroll
  for (int c = 0; c < NBCH; ++c) stB(0, c);
  if (NT > 1) {
#pragma unroll
    for (int c = 0; c < NBCH; ++c) stB(1, c);
    __builtin_amdgcn_sched_barrier(0);
    asm volatile("s_waitcnt vmcnt(%0)" ::"i"(NBCH));
  } else {
    __builtin_amdgcn_sched_barrier(0);
    asm volatile("s_waitcnt vmcnt(0)");
  }
  __builtin_amdgcn_sched_barrier(0);
  __builtin_amdgcn_s_barrier();
  rdAV(avA, smem, 0);
  __builtin_amdgcn_sched_barrier(0);

  for (int t = 0; t < NT; ++t) {
    const char* Ab = smem + ((t & 1) << 15);
    const char* AbN = smem + (((t + 1) & 1) << 15);
    const char* Bb = smem + 65536 + (t & 1) * BBYTES;
    // ph0
    rdBV(Bb);
    rdAV(avB, Ab, 1);
    if (t + 1 < NT) stA(t + 1, 0);
    __builtin_amdgcn_sched_barrier(0);
    asm volatile("s_waitcnt lgkmcnt(4)");
    __builtin_amdgcn_sched_barrier(0);
    MM(0, avA)
    // ph1
    rdAV(avA, Ab, 2);
    if (t + 1 < NT) stA(t + 1, 1);
    __builtin_amdgcn_sched_barrier(0);
    asm volatile("s_waitcnt lgkmcnt(4)");
    __builtin_amdgcn_sched_barrier(0);
    MM(1, avB)
    // ph2: all waves' B(t) reads retired -> B-buf chunks write-safe
    __builtin_amdgcn_s_barrier();
    rdAV(avB, Ab, 3);
    if (t + 2 < NT) {
      stB(t + 2, 0);
      stB(t + 2, 1);
    }
    __builtin_amdgcn_sched_barrier(0);
    asm volatile("s_waitcnt lgkmcnt(4)");
    __builtin_amdgcn_sched_barrier(0);
    MM(2, avA)
    // ph3: hard sync (A(t+1),B(t+1) landed; only ph2's 2 B-loads outstanding)
    asm volatile("s_waitcnt lgkmcnt(0)");
    if (t + 2 < NT)
      asm volatile("s_waitcnt vmcnt(2)");
    else
      asm volatile("s_waitcnt vmcnt(0)");
    __builtin_amdgcn_sched_barrier(0);
    __builtin_amdgcn_s_barrier();
    if (t + 1 < NT) rdAV(avA, AbN, 0);
    if (t + 2 < NT) {
#pragma unroll
      for (int c = 2; c < NBCH; ++c) stB(t + 2, c);
    }
    __builtin_amdgcn_sched_barrier(0);
    MM(3, avB)
  }
#undef MM

  const bool z0 = (blockIdx.y == 0);
#pragma unroll
  for (int m = 0; m < 8; ++m) {
#pragma unroll
    for (int n = 0; n < NV; ++n) {
#pragma unroll
      for (int j = 0; j < 4; ++j) {
        long row = bm + (wr << 7) + (m << 4) + (lk << 2) + j;
        long col = bn + wc * WCOLS + (n << 4) + lr;
        float v = acc[m][n][j];
        if constexpr (EPI == E_QKV) {
          if (col < 2048)
            ((u16*)C)[row * 2048 + col] = f2bf(v);
          else
            ((u16*)C2)[(col - 2048) * (long)N_ + row] = f2bf(v);
        } else if constexpr (EPI == E_SMASK) {
          v *= scale;
          if (mask[row * Ndim + col]) v = -1e9f;
          ((u16*)C)[row * Ndim + col] = f2bf(v);  // bf16 scores
        } else if constexpr (EPI == E_PART) {
          ((u16*)C)[(long)blockIdx.y * zstr + row * Ndim + col] =
              f2bf(v + ((z0 && bias) ? bias[col] : 0.f));
        } else if constexpr (EPI == E_GELU) {
          ((u16*)C)[row * Ndim + col] = f2bf(gelu_fast(v + bias[col]));
        }
      }
    }
  }
}

// ---------------- 128x128 kernel for the small head GEMM ----------------
__global__ __launch_bounds__(256) void gemm_nt_bias(
    const u16* __restrict__ A, const u16* __restrict__ B, float* __restrict__ C,
    int Ndim, int K, int lda, int ldb, const float* __restrict__ bias) {
  __shared__ u16 As[2][128 * 32];
  __shared__ u16 Bs[2][128 * 32];
  const int tid = threadIdx.x;
  const int lane = tid & 63;
  const int wid = tid >> 6;
  const int wr = wid >> 1;
  const int wc = wid & 1;
  const int lr = lane & 15;
  const int lk = lane >> 4;
  const long bm = (long)blockIdx.x * 128;
  const long bn = (long)blockIdx.y * 128;

  f32x4 acc[4][4];
#pragma unroll
  for (int i = 0; i < 4; ++i)
#pragma unroll
    for (int j = 0; j < 4; ++j) acc[i][j] = f32x4{0.f, 0.f, 0.f, 0.f};

  auto stage = [&](int buf, long k0) {
#pragma unroll
    for (int i = 0; i < 2; ++i) {
      int c = tid + i * 256;
      gl_lds16(A + (bm + (c >> 2)) * (long)lda + k0 + (c & 3) * 8, As[buf] + c * 8);
    }
#pragma unroll
    for (int i = 0; i < 2; ++i) {
      int c = tid + i * 256;
      gl_lds16(B + (bn + (c >> 2)) * (long)ldb + k0 + (c & 3) * 8, Bs[buf] + c * 8);
    }
  };

  stage(0, 0);
  __syncthreads();
  const int nt = K / 32;
  int cur = 0;
  for (int t = 0; t < nt; ++t) {
    if (t + 1 < nt) stage(cur ^ 1, (long)(t + 1) * 32);
    bf16x8 av[4], bv[4];
#pragma unroll
    for (int mr = 0; mr < 4; ++mr)
      av[mr] = *(const bf16x8*)(As[cur] + (wr * 64 + mr * 16 + lr) * 32 + lk * 8);
#pragma unroll
    for (int nr = 0; nr < 4; ++nr)
      bv[nr] = *(const bf16x8*)(Bs[cur] + (wc * 64 + nr * 16 + lr) * 32 + lk * 8);
#pragma unroll
    for (int mr = 0; mr < 4; ++mr)
#pragma unroll
      for (int nr = 0; nr < 4; ++nr)
        acc[mr][nr] = __builtin_amdgcn_mfma_f32_16x16x32_bf16(av[mr], bv[nr], acc[mr][nr], 0, 0, 0);
    __syncthreads();
    cur ^= 1;
  }
#pragma unroll
  for (int mr = 0; mr < 4; ++mr)
#pragma unroll
    for (int nr = 0; nr < 4; ++nr)
#pragma unroll
      for (int j = 0; j < 4; ++j) {
        long row = bm + wr * 64 + mr * 16 + lk * 4 + j;
        long col = bn + wc * 64 + nr * 16 + lr;
        C[row * Ndim + col] = acc[mr][nr][j] + bias[col];
      }
}

// out[c*R + r] = bf16(in[r*C + c]); z selects among up to 3 sources -> dst+z*R*C
__global__ __launch_bounds__(256) void tcvt3(const float* __restrict__ in0,
                                             const float* __restrict__ in1,
                                             const float* __restrict__ in2,
                                             u16* __restrict__ out, int R, int C) {
  __shared__ float tile[32][33];
  const float* in = (blockIdx.z == 0) ? in0 : (blockIdx.z == 1 ? in1 : in2);
  u16* dst = out + (size_t)blockIdx.z * R * C;
  int bx = blockIdx.x * 32;
  int by = blockIdx.y * 32;
  int tx = threadIdx.x & 31;
  int ty = threadIdx.x >> 5;
#pragma unroll
  for (int i = 0; i < 32; i += 8)
    tile[ty + i][tx] = in[(long)(by + ty + i) * C + bx + tx];
  __syncthreads();
#pragma unroll
  for (int i = 0; i < 32; i += 8)
    dst[(long)(bx + ty + i) * R + by + tx] = f2bf(tile[tx][ty + i]);
}

__global__ void copy_usex(const float* __restrict__ x, float* __restrict__ xf,
                          u16* __restrict__ xb, long n) {
  long i = (long)blockIdx.x * blockDim.x + threadIdx.x;
  if (i < n) {
    float v = x[i];
    xf[i] = v;
    xb[i] = f2bf(v);
  }
}

__global__ void mask_zero(const float* __restrict__ x, const int* __restrict__ mask_nodes,
                          const int* __restrict__ gene_idx, float* __restrict__ xf,
                          u16* __restrict__ xb, float* __restrict__ x_init) {
  int m = blockIdx.x;
  int k = threadIdx.x;
  if (k >= KG) return;
  int row = mask_nodes[m];
  int col = gene_idx[m * KG + k];
  x_init[m * KG + k] = x[(long)row * D_ + col];
  xf[(long)row * D_ + col] = 0.f;
  xb[(long)row * D_ + col] = 0;
}

// of/ob = LayerNorm(sum_z bf16(y[z*ystr]) + r) * g + b  (one block per row)
template <int NY>
__global__ __launch_bounds__(256) void add_ln(const u16* __restrict__ y, long ystr,
                                              const float* __restrict__ r,
                                              const float* __restrict__ g,
                                              const float* __restrict__ b,
                                              float* __restrict__ of, u16* __restrict__ ob) {
  int row = blockIdx.x;
  const int gi = threadIdx.x * 4;
  const long base = (long)row * D_ + gi;
  f32x4 rv = *(const f32x4*)(r + base);
  u16x4 yv[NY];
#pragma unroll
  for (int z = 0; z < NY; ++z) yv[z] = *(const u16x4*)(y + z * ystr + base);
  float v[4];
  float s = 0.f, ss = 0.f;
#pragma unroll
  for (int i = 0; i < 4; ++i) {
    float t = rv[i];
#pragma unroll
    for (int z = 0; z < NY; ++z) t += bf2f(yv[z][i]);
    v[i] = t;
    s += t;
    ss += t * t;
  }
#pragma unroll
  for (int o = 32; o > 0; o >>= 1) {
    s += __shfl_down(s, o, 64);
    ss += __shfl_down(ss, o, 64);
  }
  __shared__ float red[8];
  int wid = threadIdx.x >> 6, lane = threadIdx.x & 63;
  if (lane == 0) {
    red[wid] = s;
    red[4 + wid] = ss;
  }
  __syncthreads();
  if (threadIdx.x == 0) {
    red[0] = red[0] + red[1] + red[2] + red[3];
    red[4] = red[4] + red[5] + red[6] + red[7];
  }
  __syncthreads();
  float mu = red[0] * (1.f / D_);
  float var = red[4] * (1.f / D_) - mu * mu;
  float rs = rsqrtf(var + 1e-5f);
  f32x4 gv = *(const f32x4*)(g + gi);
  f32x4 bv = *(const f32x4*)(b + gi);
  f32x4 ov;
  u16x4 obv;
#pragma unroll
  for (int i = 0; i < 4; ++i) {
    float o = (v[i] - mu) * rs * gv[i] + bv[i];
    ov[i] = o;
    obv[i] = f2bf(o);
  }
  *(f32x4*)(of + base) = ov;
  *(u16x4*)(ob + base) = obv;
}

// row softmax over N_=4096 from BF16 scores; fp32 stats; bf16 out in-place
template <bool WF32>
__global__ __launch_bounds__(256) void softmax_row(const u16* __restrict__ sin,
                                                   float* __restrict__ a32,
                                                   u16* __restrict__ a16) {
  int row = blockIdx.x;
  const long base = (long)row * N_ + threadIdx.x * 16;
  const u16* sr = sin + base;
  float v[16];
  bf16x8 h0 = *(const bf16x8*)(sr);
  bf16x8 h1 = *(const bf16x8*)(sr + 8);
#pragma unroll
  for (int j = 0; j < 8; ++j) {
    v[j] = bf2f((u16)h0[j]);
    v[8 + j] = bf2f((u16)h1[j]);
  }
  float mx = v[0];
#pragma unroll
  for (int i = 1; i < 16; ++i) mx = fmaxf(mx, v[i]);
#pragma unroll
  for (int o = 32; o > 0; o >>= 1) mx = fmaxf(mx, __shfl_down(mx, o, 64));
  __shared__ float red[8];
  int wid = threadIdx.x >> 6, lane = threadIdx.x & 63;
  if (lane == 0) red[wid] = mx;
  __syncthreads();
  if (threadIdx.x == 0) red[0] = fmaxf(fmaxf(red[0], red[1]), fmaxf(red[2], red[3]));
  __syncthreads();
  mx = red[0];
  float sum = 0.f;
#pragma unroll
  for (int i = 0; i < 16; ++i) {
    v[i] = __expf(v[i] - mx);
    sum += v[i];
  }
#pragma unroll
  for (int o = 32; o > 0; o >>= 1) sum += __shfl_down(sum, o, 64);
  if (lane == 0) red[4 + wid] = sum;
  __syncthreads();
  if (threadIdx.x == 0) red[4] = red[4] + red[5] + red[6] + red[7];
  __syncthreads();
  float inv = 1.f / red[4];
  bf16x8 o0, o1;
#pragma unroll
  for (int j = 0; j < 8; ++j) {
    float p0 = v[j] * inv, p1 = v[8 + j] * inv;
    o0[j] = (short)f2bf(p0);
    o1[j] = (short)f2bf(p1);
    if constexpr (WF32) {
      a32[base + j] = p0;
      a32[base + 8 + j] = p1;
    }
  }
  *(bf16x8*)(a16 + base) = o0;
  *(bf16x8*)(a16 + base + 8) = o1;
}

__global__ void gather_rows(const u16* __restrict__ src, const int* __restrict__ mask_nodes,
                            u16* __restrict__ dst) {
  int m = blockIdx.x;
  int row = mask_nodes[m];
  for (int i = threadIdx.x; i < D_; i += 256)
    dst[(long)m * D_ + i] = src[(long)row * D_ + i];
}

__global__ void gather_recon(const float* __restrict__ h, const int* __restrict__ gene_idx,
                             float* __restrict__ xr) {
  int m = blockIdx.x;
  int k = threadIdx.x;
  if (k >= KG) return;
  xr[m * KG + k] = h[(long)m * D_ + gene_idx[m * KG + k]];
}

extern "C" void kernel_launch(void* const* d_in, const int* in_sizes, int n_in,
                              void* d_out, int out_size, void* d_ws, size_t ws_size,
                              hipStream_t stream) {
  const float* x = (const float*)d_in[0];
  const unsigned char* real_mask = (const unsigned char*)d_in[1];
  const int* mask_nodes = (const int*)d_in[3];
  const int* gene_idx = (const int*)d_in[4];
  const float* wq1 = (const float*)d_in[5];
  const float* wk1 = (const float*)d_in[6];
  const float* wv1 = (const float*)d_in[7];
  const float* g1 = (const float*)d_in[8];
  const float* be1 = (const float*)d_in[9];
  const float* fw1 = (const float*)d_in[10];
  const float* fb1 = (const float*)d_in[11];
  const float* fw2 = (const float*)d_in[12];
  const float* fb2 = (const float*)d_in[13];
  const float* g2 = (const float*)d_in[14];
  const float* be2 = (const float*)d_in[15];
  const float* wq2 = (const float*)d_in[16];
  const float* wk2 = (const float*)d_in[17];
  const float* wv2 = (const float*)d_in[18];
  const float* g3 = (const float*)d_in[19];
  const float* be3 = (const float*)d_in[20];
  const float* hw1 = (const float*)d_in[21];
  const float* hb1 = (const float*)d_in[22];
  const float* hw2 = (const float*)d_in[23];
  const float* hb2 = (const float*)d_in[24];
  const float* g4 = (const float*)d_in[25];
  const float* be4 = (const float*)d_in[26];
  const float* head_w = (const float*)d_in[27];
  const float* head_b = (const float*)d_in[28];

  float* out_xinit = (float*)d_out;
  float* out_xrecon = out_xinit + (long)M_ * KG;
  float* out_enc = out_xrecon + (long)M_ * KG;
  float* out_recon = out_enc + (long)N_ * N_;

  hipFuncSetAttribute((const void*)gemm256<E_QKV, 192>, hipFuncAttributeMaxDynamicSharedMemorySize, SMEM_BYTES);
  hipFuncSetAttribute((const void*)gemm256<E_SMASK>, hipFuncAttributeMaxDynamicSharedMemorySize, SMEM_BYTES);
  hipFuncSetAttribute((const void*)gemm256<E_PART>, hipFuncAttributeMaxDynamicSharedMemorySize, SMEM_BYTES);
  hipFuncSetAttribute((const void*)gemm256<E_GELU>, hipFuncAttributeMaxDynamicSharedMemorySize, SMEM_BYTES);

  char* w = (char*)d_ws;
  size_t off = 0;
  auto alloc = [&](size_t bytes) {
    void* p = w + off;
    off += (bytes + 255) & ~(size_t)255;
    return p;
  };
  float* useXf = (float*)alloc((size_t)N_ * D_ * 4);
  u16* useXb = (u16*)alloc((size_t)N_ * D_ * 2);
  u16* wslot = (u16*)alloc((size_t)D_ * F_ * 2);   // weights^T / fused qkv^T
  u16* qkb = (u16*)alloc((size_t)N_ * 2048 * 2);   // q|k  [4096][2048]
  u16* vT = (u16*)alloc((size_t)D_ * N_ * 2);      // v^T  [1024][4096]
  u16* tbuf = (u16*)alloc((size_t)N_ * F_ * 2);    // FFN intermediate bf16
  u16* aB = (u16*)alloc((size_t)N_ * N_ * 2);      // bf16 scores -> bf16 attn
  u16* gout4b = (u16*)alloc((size_t)4 * N_ * D_ * 2);  // bf16 split-K partials
  float* actA = (float*)alloc((size_t)N_ * D_ * 4);
  float* actB = (float*)alloc((size_t)N_ * D_ * 4);
  u16* actB16 = (u16*)alloc((size_t)N_ * D_ * 2);
  u16* AgB = qkb;  // gathered masked rows reuse q|k buffer

  const float scale = 1.0f / 32.0f;  // 1/sqrt(D_)
  const long nd = (long)N_ * D_;
  dim3 blk(256), blk5(512);

  copy_usex<<<dim3((unsigned)((nd + 255) / 256)), blk, 0, stream>>>(x, useXf, useXb, nd);
  mask_zero<<<dim3(M_), 320, 0, stream>>>(x, mask_nodes, gene_idx, useXf, useXb, out_xinit);

#define TCVT1(src, R, C, dst) \
  tcvt3<<<dim3((C) / 32, (R) / 32, 1), blk, 0, stream>>>(src, src, src, dst, R, C)
#define TCVTQ(s0, s1, s2, dst) \
  tcvt3<<<dim3(32, 32, 3), blk, 0, stream>>>(s0, s1, s2, dst, 1024, 1024)
#define GQKV(A)                                                                           \
  gemm256<E_QKV, 192><<<dim3(256, 1), blk5, SMEM_BYTES, stream>>>(                        \
      A, wslot, qkb, vT, 16, 16, 3072, 1024, 1024, 1024, 0, nullptr, nullptr, 0.f)
#define G256(EP, GM, GN, Z, A, B, C, C2, ND, KS, LA, LB, ZS, BI, MK, SC)                        \
  gemm256<EP><<<dim3((GM) * (GN), Z), blk5, SMEM_BYTES, stream>>>(A, B, C, C2, GM, GN, ND, KS, \
                                                                  LA, LB, ZS, BI, MK, SC)

  // ================= block 1 =================
  TCVTQ(wq1, wk1, wv1, wslot);
  GQKV(useXb);
  G256(E_SMASK, 16, 16, 1, qkb, qkb + 1024, aB, nullptr, 4096, 1024, 2048, 2048, 0, nullptr, real_mask, scale);
  softmax_row<true><<<dim3(N_), blk, 0, stream>>>(aB, out_enc, aB);
  G256(E_PART, 16, 4, 4, aB, vT, gout4b, nullptr, 1024, 1024, 4096, 4096, nd, nullptr, nullptr, 0.f);
  add_ln<4><<<dim3(N_), blk, 0, stream>>>(gout4b, nd, useXf, g1, be1, actA, actB16);
  TCVT1(fw1, D_, F_, wslot);
  G256(E_GELU, 16, 16, 1, actB16, wslot, tbuf, nullptr, 4096, 1024, 1024, 1024, 0, fb1, nullptr, 0.f);
  TCVT1(fw2, F_, D_, wslot);
  G256(E_PART, 16, 4, 4, tbuf, wslot, gout4b, nullptr, 1024, 1024, 4096, 4096, nd, fb2, nullptr, 0.f);
  add_ln<4><<<dim3(N_), blk, 0, stream>>>(gout4b, nd, actA, g2, be2, actB, actB16);

  // ================= block 2 =================
  TCVTQ(wq2, wk2, wv2, wslot);
  GQKV(actB16);
  G256(E_SMASK, 16, 16, 1, qkb, qkb + 1024, aB, nullptr, 4096, 1024, 2048, 2048, 0, nullptr, real_mask, scale);
  softmax_row<false><<<dim3(N_), blk, 0, stream>>>(aB, nullptr, aB);
  G256(E_PART, 16, 4, 4, aB, vT, gout4b, nullptr, 1024, 1024, 4096, 4096, nd, nullptr, nullptr, 0.f);
  add_ln<4><<<dim3(N_), blk, 0, stream>>>(gout4b, nd, actB, g3, be3, actA, actB16);
  TCVT1(hw1, D_, F_, wslot);
  G256(E_GELU, 16, 16, 1, actB16, wslot, tbuf, nullptr, 4096, 1024, 1024, 1024, 0, hb1, nullptr, 0.f);
  TCVT1(hw2, F_, D_, wslot);
  G256(E_PART, 16, 4, 4, tbuf, wslot, gout4b, nullptr, 1024, 1024, 4096, 4096, nd, hb2, nullptr, 0.f);
  add_ln<4><<<dim3(N_), blk, 0, stream>>>(gout4b, nd, actA, g4, be4, out_recon, actB16);

  // ================= head =================
  gather_rows<<<dim3(M_), blk, 0, stream>>>(actB16, mask_nodes, AgB);
  TCVT1(head_w, D_, D_, wslot);
  gemm_nt_bias<<<dim3(16, 8), blk, 0, stream>>>(AgB, wslot, actA, 1024, 1024, 1024, 1024, head_b);
  gather_recon<<<dim3(M_), 320, 0, stream>>>(actA, gene_idx, out_xrecon);
#undef TCVT1
#undef TCVTQ
#undef GQKV
#undef G256
}

// Round 18
// 572.777 us; speedup vs baseline: 1.0885x; 1.0885x over previous
//
#include <hip/hip_runtime.h>
#include <math.h>
#include <stdint.h>

typedef unsigned short u16;
typedef __attribute__((ext_vector_type(8))) short bf16x8;
typedef __attribute__((ext_vector_type(4))) float f32x4;
typedef __attribute__((ext_vector_type(4))) unsigned short u16x4;

#define N_ 4096
#define D_ 1024
#define F_ 4096
#define M_ 2048
#define KG 307

__device__ __forceinline__ u16 f2bf(float f) {
  unsigned int u = __float_as_uint(f);
  unsigned int r = u + 0x7fffu + ((u >> 16) & 1u);
  return (u16)(r >> 16);
}

__device__ __forceinline__ float bf2f(u16 u) {
  return __uint_as_float((unsigned)u << 16);
}

// GELU via Abramowitz-Stegun 7.1.26 erf (|err| <= 1.5e-7). Verified r16.
__device__ __forceinline__ float gelu_fast(float t) {
  float x = t * 0.70710678118654752f;
  float ax = fabsf(x);
  float u = __builtin_amdgcn_rcpf(fmaf(0.3275911f, ax, 1.0f));
  float poly =
      u * fmaf(u, fmaf(u, fmaf(u, fmaf(u, 1.061405429f, -1.453152027f), 1.421413741f),
                       -0.284496736f),
               0.254829592f);
  float erfabs = fmaf(-poly, __expf(-ax * ax), 1.0f);
  float er = copysignf(erfabs, x);
  return 0.5f * t * (1.0f + er);
}

__device__ __forceinline__ void gl_lds16(const u16* g, u16* l) {
  __builtin_amdgcn_global_load_lds(
      (__attribute__((address_space(1))) void*)(void*)g,
      (__attribute__((address_space(3))) void*)(void*)l,
      16, 0, 0);
}

enum { E_QKV = 0, E_SMASK = 1, E_PART = 2, E_GELU = 3 };
#define SMEM_BYTES 131072

// ============================================================================
// 256xTN 8-wave GEMM (TN in {256,192,128}), BK=64, cross-phase pipelined.
// B staged in 64-row chunks (1 load/thread each -> vmcnt ledger is
// TN-independent: 2 chunks at ph2, remainder post-ph3-barrier).
// ============================================================================
template <int EPI, int TN = 256>
__global__ __launch_bounds__(512, 2) void gemm256(
    const u16* __restrict__ A, const u16* __restrict__ B,
    void* __restrict__ C, void* __restrict__ C2,
    int gridM, int gridN, int Ndim, int Ksp, int lda, int ldb, long zstr,
    const float* __restrict__ bias, const unsigned char* __restrict__ mask,
    float scale) {
  constexpr int NV = TN / 64;       // B fragments per wave
  constexpr int WCOLS = TN / 4;     // cols per wave
  constexpr int NBCH = TN / 64;     // 64-row B chunks per tile
  constexpr int BBYTES = TN * 128;  // B dbuf bytes
  extern __shared__ __align__(16) char smem[];
  const int tid = threadIdx.x;
  const int lane = tid & 63;
  const int wid = tid >> 6;
  const int wr = wid >> 2;
  const int wc = wid & 3;
  const int lr = lane & 15;
  const int lk = lane >> 4;

  const int nwg = gridM * gridN;
  const int bid = blockIdx.x;
  const int q8 = nwg >> 3, r8 = nwg & 7;
  const int xcd = bid & 7, ii = bid >> 3;
  int wg = (xcd < r8 ? xcd * (q8 + 1) : r8 * (q8 + 1) + (xcd - r8) * q8) + ii;
  const int rowblk = wg / (gridN << 2);
  const int rem = wg - rowblk * (gridN << 2);
  const int mrem = gridM - (rowblk << 2);
  int mtile, ntile;
  if (mrem >= 4) {
    ntile = rem >> 2;
    mtile = (rowblk << 2) + (rem & 3);
  } else {
    ntile = rem / mrem;
    mtile = (rowblk << 2) + (rem - ntile * mrem);
  }
  const long bm = (long)mtile * 256;
  const long bn = (long)ntile * TN;
  const long koff = (long)blockIdx.y * Ksp;
  const int NT = Ksp >> 6;

  auto stA = [&](int t, int h) {  // A half-tile: 128 rows, 2 loads/thread
    char* base = smem + ((t & 1) << 15) + (h << 14);
    const long k0 = koff + ((long)t << 6);
#pragma unroll
    for (int j = 0; j < 2; ++j) {
      int o = tid + (j << 9);
      int r = o >> 3, s = o & 7;
      gl_lds16(A + (bm + (h << 7) + r) * (long)lda + k0 + ((s ^ (r & 7)) << 3),
               (u16*)(base + o * 16));
    }
  };
  auto stB = [&](int t, int c) {  // B chunk: 64 rows, 1 load/thread
    char* base = smem + 65536 + (t & 1) * BBYTES + (c << 13);
    const long k0 = koff + ((long)t << 6);
    int o = tid;
    int r = o >> 3, s = o & 7;
    gl_lds16(B + (bn + (c << 6) + r) * (long)ldb + k0 + ((s ^ (r & 7)) << 3),
             (u16*)(base + o * 16));
  };

  bf16x8 avA[2][2], avB[2][2], bv[NV][2];
  f32x4 acc[8][NV];
#pragma unroll
  for (int m = 0; m < 8; ++m)
#pragma unroll
    for (int n = 0; n < NV; ++n) acc[m][n] = f32x4{0.f, 0.f, 0.f, 0.f};

  auto rdAV = [&](bf16x8(&av)[2][2], const char* Ab_, int q) {
#pragma unroll
    for (int e = 0; e < 2; ++e)
#pragma unroll
      for (int ks = 0; ks < 2; ++ks) {
        int r = (wr << 7) + (q << 5) + (e << 4) + lr;
        av[e][ks] = *(const bf16x8*)(Ab_ + r * 128 + ((((ks << 2) | lk) ^ (r & 7)) << 4));
      }
  };
  auto rdBV = [&](const char* Bb_) {
#pragma unroll
    for (int n = 0; n < NV; ++n)
#pragma unroll
      for (int ks = 0; ks < 2; ++ks) {
        int r = wc * WCOLS + (n << 4) + lr;
        bv[n][ks] = *(const bf16x8*)(Bb_ + r * 128 + ((((ks << 2) | lk) ^ (r & 7)) << 4));
      }
  };

#define MM(Q, AV)                                                              \
  __builtin_amdgcn_s_setprio(1);                                               \
  _Pragma("unroll") for (int e = 0; e < 2; ++e)                                \
  _Pragma("unroll") for (int n = 0; n < NV; ++n)                               \
  _Pragma("unroll") for (int ks = 0; ks < 2; ++ks)                             \
      acc[((Q) << 1) | e][n] = __builtin_amdgcn_mfma_f32_16x16x32_bf16(        \
          AV[e][ks], bv[n][ks], acc[((Q) << 1) | e][n], 0, 0, 0);              \
  __builtin_amdgcn_s_setprio(0);                                               \
  __builtin_amdgcn_sched_barrier(0);

  stA(0, 0);
  stA(0, 1);
#pragma unroll
  for (int c = 0; c < NBCH; ++c) stB(0, c);
  if (NT > 1) {
#pragma unroll
    for (int c = 0; c < NBCH; ++c) stB(1, c);
    __builtin_amdgcn_sched_barrier(0);
    asm volatile("s_waitcnt vmcnt(%0)" ::"i"(NBCH));
  } else {
    __builtin_amdgcn_sched_barrier(0);
    asm volatile("s_waitcnt vmcnt(0)");
  }
  __builtin_amdgcn_sched_barrier(0);
  __builtin_amdgcn_s_barrier();
  rdAV(avA, smem, 0);
  __builtin_amdgcn_sched_barrier(0);

  for (int t = 0; t < NT; ++t) {
    const char* Ab = smem + ((t & 1) << 15);
    const char* AbN = smem + (((t + 1) & 1) << 15);
    const char* Bb = smem + 65536 + (t & 1) * BBYTES;
    rdBV(Bb);
    rdAV(avB, Ab, 1);
    if (t + 1 < NT) stA(t + 1, 0);
    __builtin_amdgcn_sched_barrier(0);
    asm volatile("s_waitcnt lgkmcnt(4)");
    __builtin_amdgcn_sched_barrier(0);
    MM(0, avA)
    rdAV(avA, Ab, 2);
    if (t + 1 < NT) stA(t + 1, 1);
    __builtin_amdgcn_sched_barrier(0);
    asm volatile("s_waitcnt lgkmcnt(4)");
    __builtin_amdgcn_sched_barrier(0);
    MM(1, avB)
    __builtin_amdgcn_s_barrier();
    rdAV(avB, Ab, 3);
    if (t + 2 < NT) {
      stB(t + 2, 0);
      stB(t + 2, 1);
    }
    __builtin_amdgcn_sched_barrier(0);
    asm volatile("s_waitcnt lgkmcnt(4)");
    __builtin_amdgcn_sched_barrier(0);
    MM(2, avA)
    asm volatile("s_waitcnt lgkmcnt(0)");
    if (t + 2 < NT)
      asm volatile("s_waitcnt vmcnt(2)");
    else
      asm volatile("s_waitcnt vmcnt(0)");
    __builtin_amdgcn_sched_barrier(0);
    __builtin_amdgcn_s_barrier();
    if (t + 1 < NT) rdAV(avA, AbN, 0);
    if (t + 2 < NT) {
#pragma unroll
      for (int c = 2; c < NBCH; ++c) stB(t + 2, c);
    }
    __builtin_amdgcn_sched_barrier(0);
    MM(3, avB)
  }
#undef MM

  const bool z0 = (blockIdx.y == 0);
#pragma unroll
  for (int m = 0; m < 8; ++m) {
#pragma unroll
    for (int n = 0; n < NV; ++n) {
#pragma unroll
      for (int j = 0; j < 4; ++j) {
        long row = bm + (wr << 7) + (m << 4) + (lk << 2) + j;
        long col = bn + wc * WCOLS + (n << 4) + lr;
        float v = acc[m][n][j];
        if constexpr (EPI == E_QKV) {
          if (col < 2048)
            ((u16*)C)[row * 2048 + col] = f2bf(v);
          else
            ((u16*)C2)[(col - 2048) * (long)N_ + row] = f2bf(v);
        } else if constexpr (EPI == E_SMASK) {
          v *= scale;
          if (mask[row * Ndim + col]) v = -1e9f;
          ((u16*)C)[row * Ndim + col] = f2bf(v);  // bf16 scores
        } else if constexpr (EPI == E_PART) {
          ((u16*)C)[(long)blockIdx.y * zstr + row * Ndim + col] =
              f2bf(v + ((z0 && bias) ? bias[col] : 0.f));
        } else if constexpr (EPI == E_GELU) {
          ((u16*)C)[row * Ndim + col] = f2bf(gelu_fast(v + bias[col]));
        }
      }
    }
  }
}

// ---------------- 128x128 kernel for the small head GEMM ----------------
__global__ __launch_bounds__(256) void gemm_nt_bias(
    const u16* __restrict__ A, const u16* __restrict__ B, float* __restrict__ C,
    int Ndim, int K, int lda, int ldb, const float* __restrict__ bias) {
  __shared__ u16 As[2][128 * 32];
  __shared__ u16 Bs[2][128 * 32];
  const int tid = threadIdx.x;
  const int lane = tid & 63;
  const int wid = tid >> 6;
  const int wr = wid >> 1;
  const int wc = wid & 1;
  const int lr = lane & 15;
  const int lk = lane >> 4;
  const long bm = (long)blockIdx.x * 128;
  const long bn = (long)blockIdx.y * 128;

  f32x4 acc[4][4];
#pragma unroll
  for (int i = 0; i < 4; ++i)
#pragma unroll
    for (int j = 0; j < 4; ++j) acc[i][j] = f32x4{0.f, 0.f, 0.f, 0.f};

  auto stage = [&](int buf, long k0) {
#pragma unroll
    for (int i = 0; i < 2; ++i) {
      int c = tid + i * 256;
      gl_lds16(A + (bm + (c >> 2)) * (long)lda + k0 + (c & 3) * 8, As[buf] + c * 8);
    }
#pragma unroll
    for (int i = 0; i < 2; ++i) {
      int c = tid + i * 256;
      gl_lds16(B + (bn + (c >> 2)) * (long)ldb + k0 + (c & 3) * 8, Bs[buf] + c * 8);
    }
  };

  stage(0, 0);
  __syncthreads();
  const int nt = K / 32;
  int cur = 0;
  for (int t = 0; t < nt; ++t) {
    if (t + 1 < nt) stage(cur ^ 1, (long)(t + 1) * 32);
    bf16x8 av[4], bv[4];
#pragma unroll
    for (int mr = 0; mr < 4; ++mr)
      av[mr] = *(const bf16x8*)(As[cur] + (wr * 64 + mr * 16 + lr) * 32 + lk * 8);
#pragma unroll
    for (int nr = 0; nr < 4; ++nr)
      bv[nr] = *(const bf16x8*)(Bs[cur] + (wc * 64 + nr * 16 + lr) * 32 + lk * 8);
#pragma unroll
    for (int mr = 0; mr < 4; ++mr)
#pragma unroll
      for (int nr = 0; nr < 4; ++nr)
        acc[mr][nr] = __builtin_amdgcn_mfma_f32_16x16x32_bf16(av[mr], bv[nr], acc[mr][nr], 0, 0, 0);
    __syncthreads();
    cur ^= 1;
  }
#pragma unroll
  for (int mr = 0; mr < 4; ++mr)
#pragma unroll
    for (int nr = 0; nr < 4; ++nr)
#pragma unroll
      for (int j = 0; j < 4; ++j) {
        long row = bm + wr * 64 + mr * 16 + lk * 4 + j;
        long col = bn + wc * 64 + nr * 16 + lr;
        C[row * Ndim + col] = acc[mr][nr][j] + bias[col];
      }
}

// out[c*R + r] = bf16(in[r*C + c]); z selects among up to 3 sources -> dst+z*R*C
__global__ __launch_bounds__(256) void tcvt3(const float* __restrict__ in0,
                                             const float* __restrict__ in1,
                                             const float* __restrict__ in2,
                                             u16* __restrict__ out, int R, int C) {
  __shared__ float tile[32][33];
  const float* in = (blockIdx.z == 0) ? in0 : (blockIdx.z == 1 ? in1 : in2);
  u16* dst = out + (size_t)blockIdx.z * R * C;
  int bx = blockIdx.x * 32;
  int by = blockIdx.y * 32;
  int tx = threadIdx.x & 31;
  int ty = threadIdx.x >> 5;
#pragma unroll
  for (int i = 0; i < 32; i += 8)
    tile[ty + i][tx] = in[(long)(by + ty + i) * C + bx + tx];
  __syncthreads();
#pragma unroll
  for (int i = 0; i < 32; i += 8)
    dst[(long)(bx + ty + i) * R + by + tx] = f2bf(tile[tx][ty + i]);
}

__global__ void copy_usex(const float* __restrict__ x, u16* __restrict__ xb, long n) {
  long i = (long)blockIdx.x * blockDim.x + threadIdx.x;
  if (i < n) xb[i] = f2bf(x[i]);
}

__global__ void mask_zero(const float* __restrict__ x, const int* __restrict__ mask_nodes,
                          const int* __restrict__ gene_idx, u16* __restrict__ xb,
                          float* __restrict__ x_init) {
  int m = blockIdx.x;
  int k = threadIdx.x;
  if (k >= KG) return;
  int row = mask_nodes[m];
  int col = gene_idx[m * KG + k];
  x_init[m * KG + k] = x[(long)row * D_ + col];
  xb[(long)row * D_ + col] = 0;
}

// ob = bf16(LayerNorm(sum_z bf16(y[z*ystr]) + bf16 r) * g + b); optional fp32 of.
// One block per row; thread t owns contiguous [t*4, t*4+4) — vectorized.
template <int NY, bool WOF>
__global__ __launch_bounds__(256) void add_ln(const u16* __restrict__ y, long ystr,
                                              const u16* __restrict__ r,
                                              const float* __restrict__ g,
                                              const float* __restrict__ b,
                                              float* __restrict__ of, u16* __restrict__ ob) {
  int row = blockIdx.x;
  const int gi = threadIdx.x * 4;
  const long base = (long)row * D_ + gi;
  u16x4 rv = *(const u16x4*)(r + base);
  u16x4 yv[NY];
#pragma unroll
  for (int z = 0; z < NY; ++z) yv[z] = *(const u16x4*)(y + z * ystr + base);
  float v[4];
  float s = 0.f, ss = 0.f;
#pragma unroll
  for (int i = 0; i < 4; ++i) {
    float t = bf2f(rv[i]);
#pragma unroll
    for (int z = 0; z < NY; ++z) t += bf2f(yv[z][i]);
    v[i] = t;
    s += t;
    ss += t * t;
  }
#pragma unroll
  for (int o = 32; o > 0; o >>= 1) {
    s += __shfl_down(s, o, 64);
    ss += __shfl_down(ss, o, 64);
  }
  __shared__ float red[8];
  int wid = threadIdx.x >> 6, lane = threadIdx.x & 63;
  if (lane == 0) {
    red[wid] = s;
    red[4 + wid] = ss;
  }
  __syncthreads();
  if (threadIdx.x == 0) {
    red[0] = red[0] + red[1] + red[2] + red[3];
    red[4] = red[4] + red[5] + red[6] + red[7];
  }
  __syncthreads();
  float mu = red[0] * (1.f / D_);
  float var = red[4] * (1.f / D_) - mu * mu;
  float rs = rsqrtf(var + 1e-5f);
  f32x4 gv = *(const f32x4*)(g + gi);
  f32x4 bv = *(const f32x4*)(b + gi);
  f32x4 ov;
  u16x4 obv;
#pragma unroll
  for (int i = 0; i < 4; ++i) {
    float o = (v[i] - mu) * rs * gv[i] + bv[i];
    ov[i] = o;
    obv[i] = f2bf(o);
  }
  if constexpr (WOF) *(f32x4*)(of + base) = ov;
  *(u16x4*)(ob + base) = obv;
}

// row softmax over N_=4096 from BF16 scores; fp32 stats; bf16 out in-place
template <bool WF32>
__global__ __launch_bounds__(256) void softmax_row(const u16* __restrict__ sin,
                                                   float* __restrict__ a32,
                                                   u16* __restrict__ a16) {
  int row = blockIdx.x;
  const long base = (long)row * N_ + threadIdx.x * 16;
  const u16* sr = sin + base;
  float v[16];
  bf16x8 h0 = *(const bf16x8*)(sr);
  bf16x8 h1 = *(const bf16x8*)(sr + 8);
#pragma unroll
  for (int j = 0; j < 8; ++j) {
    v[j] = bf2f((u16)h0[j]);
    v[8 + j] = bf2f((u16)h1[j]);
  }
  float mx = v[0];
#pragma unroll
  for (int i = 1; i < 16; ++i) mx = fmaxf(mx, v[i]);
#pragma unroll
  for (int o = 32; o > 0; o >>= 1) mx = fmaxf(mx, __shfl_down(mx, o, 64));
  __shared__ float red[8];
  int wid = threadIdx.x >> 6, lane = threadIdx.x & 63;
  if (lane == 0) red[wid] = mx;
  __syncthreads();
  if (threadIdx.x == 0) red[0] = fmaxf(fmaxf(red[0], red[1]), fmaxf(red[2], red[3]));
  __syncthreads();
  mx = red[0];
  float sum = 0.f;
#pragma unroll
  for (int i = 0; i < 16; ++i) {
    v[i] = __expf(v[i] - mx);
    sum += v[i];
  }
#pragma unroll
  for (int o = 32; o > 0; o >>= 1) sum += __shfl_down(sum, o, 64);
  if (lane == 0) red[4 + wid] = sum;
  __syncthreads();
  if (threadIdx.x == 0) red[4] = red[4] + red[5] + red[6] + red[7];
  __syncthreads();
  float inv = 1.f / red[4];
  bf16x8 o0, o1;
#pragma unroll
  for (int j = 0; j < 8; ++j) {
    float p0 = v[j] * inv, p1 = v[8 + j] * inv;
    o0[j] = (short)f2bf(p0);
    o1[j] = (short)f2bf(p1);
    if constexpr (WF32) {
      a32[base + j] = p0;
      a32[base + 8 + j] = p1;
    }
  }
  *(bf16x8*)(a16 + base) = o0;
  *(bf16x8*)(a16 + base + 8) = o1;
}

__global__ void gather_rows(const u16* __restrict__ src, const int* __restrict__ mask_nodes,
                            u16* __restrict__ dst) {
  int m = blockIdx.x;
  int row = mask_nodes[m];
  for (int i = threadIdx.x; i < D_; i += 256)
    dst[(long)m * D_ + i] = src[(long)row * D_ + i];
}

__global__ void gather_recon(const float* __restrict__ h, const int* __restrict__ gene_idx,
                             float* __restrict__ xr) {
  int m = blockIdx.x;
  int k = threadIdx.x;
  if (k >= KG) return;
  xr[m * KG + k] = h[(long)m * D_ + gene_idx[m * KG + k]];
}

extern "C" void kernel_launch(void* const* d_in, const int* in_sizes, int n_in,
                              void* d_out, int out_size, void* d_ws, size_t ws_size,
                              hipStream_t stream) {
  const float* x = (const float*)d_in[0];
  const unsigned char* real_mask = (const unsigned char*)d_in[1];
  const int* mask_nodes = (const int*)d_in[3];
  const int* gene_idx = (const int*)d_in[4];
  const float* wq1 = (const float*)d_in[5];
  const float* wk1 = (const float*)d_in[6];
  const float* wv1 = (const float*)d_in[7];
  const float* g1 = (const float*)d_in[8];
  const float* be1 = (const float*)d_in[9];
  const float* fw1 = (const float*)d_in[10];
  const float* fb1 = (const float*)d_in[11];
  const float* fw2 = (const float*)d_in[12];
  const float* fb2 = (const float*)d_in[13];
  const float* g2 = (const float*)d_in[14];
  const float* be2 = (const float*)d_in[15];
  const float* wq2 = (const float*)d_in[16];
  const float* wk2 = (const float*)d_in[17];
  const float* wv2 = (const float*)d_in[18];
  const float* g3 = (const float*)d_in[19];
  const float* be3 = (const float*)d_in[20];
  const float* hw1 = (const float*)d_in[21];
  const float* hb1 = (const float*)d_in[22];
  const float* hw2 = (const float*)d_in[23];
  const float* hb2 = (const float*)d_in[24];
  const float* g4 = (const float*)d_in[25];
  const float* be4 = (const float*)d_in[26];
  const float* head_w = (const float*)d_in[27];
  const float* head_b = (const float*)d_in[28];

  float* out_xinit = (float*)d_out;
  float* out_xrecon = out_xinit + (long)M_ * KG;
  float* out_enc = out_xrecon + (long)M_ * KG;
  float* out_recon = out_enc + (long)N_ * N_;

  hipFuncSetAttribute((const void*)gemm256<E_QKV, 192>, hipFuncAttributeMaxDynamicSharedMemorySize, SMEM_BYTES);
  hipFuncSetAttribute((const void*)gemm256<E_SMASK>, hipFuncAttributeMaxDynamicSharedMemorySize, SMEM_BYTES);
  hipFuncSetAttribute((const void*)gemm256<E_PART, 128>, hipFuncAttributeMaxDynamicSharedMemorySize, SMEM_BYTES);
  hipFuncSetAttribute((const void*)gemm256<E_GELU>, hipFuncAttributeMaxDynamicSharedMemorySize, SMEM_BYTES);

  char* w = (char*)d_ws;
  size_t off = 0;
  auto alloc = [&](size_t bytes) {
    void* p = w + off;
    off += (bytes + 255) & ~(size_t)255;
    return p;
  };
  u16* useXb = (u16*)alloc((size_t)N_ * D_ * 2);
  u16* wslot = (u16*)alloc((size_t)D_ * F_ * 2);   // weights^T / fused qkv^T
  u16* qkb = (u16*)alloc((size_t)N_ * 2048 * 2);   // q|k  [4096][2048]
  u16* vT = (u16*)alloc((size_t)D_ * N_ * 2);      // v^T  [1024][4096]
  u16* tbuf = (u16*)alloc((size_t)N_ * F_ * 2);    // FFN intermediate bf16
  u16* aB = (u16*)alloc((size_t)N_ * N_ * 2);      // bf16 scores -> bf16 attn
  u16* gout2b = (u16*)alloc((size_t)2 * N_ * D_ * 2);  // bf16 split-K partials
  u16* ab1 = (u16*)alloc((size_t)N_ * D_ * 2);     // activation ping
  u16* ab2 = (u16*)alloc((size_t)N_ * D_ * 2);     // activation pong
  u16* AgB = qkb;                // gathered masked rows reuse q|k buffer
  float* hout = (float*)gout2b;  // head fp32 out reuses partial buffer

  const float scale = 1.0f / 32.0f;  // 1/sqrt(D_)
  const long nd = (long)N_ * D_;
  dim3 blk(256), blk5(512);

  copy_usex<<<dim3((unsigned)((nd + 255) / 256)), blk, 0, stream>>>(x, useXb, nd);
  mask_zero<<<dim3(M_), 320, 0, stream>>>(x, mask_nodes, gene_idx, useXb, out_xinit);

#define TCVT1(src, R, C, dst) \
  tcvt3<<<dim3((C) / 32, (R) / 32, 1), blk, 0, stream>>>(src, src, src, dst, R, C)
#define TCVTQ(s0, s1, s2, dst) \
  tcvt3<<<dim3(32, 32, 3), blk, 0, stream>>>(s0, s1, s2, dst, 1024, 1024)
#define GQKV(A)                                                                           \
  gemm256<E_QKV, 192><<<dim3(256, 1), blk5, SMEM_BYTES, stream>>>(                        \
      A, wslot, qkb, vT, 16, 16, 3072, 1024, 1024, 1024, 0, nullptr, nullptr, 0.f)
#define GPART(A, B, BI)                                                                   \
  gemm256<E_PART, 128><<<dim3(128, 2), blk5, SMEM_BYTES, stream>>>(                       \
      A, B, gout2b, nullptr, 16, 8, 1024, 2048, 4096, 4096, nd, BI, nullptr, 0.f)
#define G256(EP, GM, GN, A, B, C, ND, KS, LA, LB, BI, MK, SC)                              \
  gemm256<EP><<<dim3((GM) * (GN), 1), blk5, SMEM_BYTES, stream>>>(                         \
      A, B, C, nullptr, GM, GN, ND, KS, LA, LB, 0, BI, MK, SC)

  // ================= block 1 =================
  TCVTQ(wq1, wk1, wv1, wslot);
  GQKV(useXb);
  G256(E_SMASK, 16, 16, qkb, qkb + 1024, aB, 4096, 1024, 2048, 2048, nullptr, real_mask, scale);
  softmax_row<true><<<dim3(N_), blk, 0, stream>>>(aB, out_enc, aB);
  GPART(aB, vT, nullptr);
  add_ln<2, false><<<dim3(N_), blk, 0, stream>>>(gout2b, nd, useXb, g1, be1, nullptr, ab1);
  TCVT1(fw1, D_, F_, wslot);
  G256(E_GELU, 16, 16, ab1, wslot, tbuf, 4096, 1024, 1024, 1024, fb1, nullptr, 0.f);
  TCVT1(fw2, F_, D_, wslot);
  GPART(tbuf, wslot, fb2);
  add_ln<2, false><<<dim3(N_), blk, 0, stream>>>(gout2b, nd, ab1, g2, be2, nullptr, ab2);

  // ================= block 2 =================
  TCVTQ(wq2, wk2, wv2, wslot);
  GQKV(ab2);
  G256(E_SMASK, 16, 16, qkb, qkb + 1024, aB, 4096, 1024, 2048, 2048, nullptr, real_mask, scale);
  softmax_row<false><<<dim3(N_), blk, 0, stream>>>(aB, nullptr, aB);
  GPART(aB, vT, nullptr);
  add_ln<2, false><<<dim3(N_), blk, 0, stream>>>(gout2b, nd, ab2, g3, be3, nullptr, ab1);
  TCVT1(hw1, D_, F_, wslot);
  G256(E_GELU, 16, 16, ab1, wslot, tbuf, 4096, 1024, 1024, 1024, hb1, nullptr, 0.f);
  TCVT1(hw2, F_, D_, wslot);
  GPART(tbuf, wslot, hb2);
  add_ln<2, true><<<dim3(N_), blk, 0, stream>>>(gout2b, nd, ab1, g4, be4, out_recon, ab2);

  // ================= head =================
  gather_rows<<<dim3(M_), blk, 0, stream>>>(ab2, mask_nodes, AgB);
  TCVT1(head_w, D_, D_, wslot);
  gemm_nt_bias<<<dim3(16, 8), blk, 0, stream>>>(AgB, wslot, hout, 1024, 1024, 1024, 1024, head_b);
  gather_recon<<<dim3(M_), 320, 0, stream>>>(hout, gene_idx, out_xrecon);
#undef TCVT1
#undef TCVTQ
#undef GQKV
#undef GPART
#undef G256
}